// Round 3
// baseline (869.489 us; speedup 1.0000x reference)
//
#include <hip/hip_runtime.h>
#include <hip/hip_bf16.h>

// ---------------------------------------------------------------------------
// GLIF3 RSNN. KEY INSIGHT: with these inputs the network is provably silent:
//   a spike needs EMA(I_ext) >= 15 (V_TH-V_RESET), but
//   |I_ext| <= sum_d max(W_in,0) ~ 6.3 absolute worst case.
// So spikes/psc/filtered are EXACTLY zero, output == b_out exactly, and
// voltage is an independent per-(b,n) linear EMA of I_ext (abs tol ~1.235).
//
// R3: single fused kernel. I_ext is never materialized: each block owns
// (16-neuron slab x all 64 batch x 100-step chunk), recomputes I via bf16
// MFMA (B-fragments hoisted into registers, x reads served by L2/L3 since
// x is 32.8 MB total), runs the voltage EMA with a 56-step warmup, and
// writes volt + the zero outputs inline (overlaps zero-store BW with MFMA).
// Safety: waves atomicMax a ws flag only if any I > 14; fallback kernel
// (full dynamics, I recomputed inline) runs only when flag > 14. The 0xAA
// ws poison decodes to a negative float => silent path taken.
// Timed-window accounting: harness poison (2 GB ws + 524 MB out) ~450 us is
// a fixed floor; our graph's floor is the 524 MB of mandatory output writes.
// ---------------------------------------------------------------------------

#define T_ 1000
#define B_ 64
#define D_ 128
#define N_ 512
#define O_ 10
#define BN_ (B_ * N_)                    // 32768
#define S_ ((size_t)T_ * BN_)            // 32,768,000 elems per big output

#define NSLABS_ 32                       // 16 neurons each
#define NCHUNK_ 10                       // 100 timesteps each
#define CHUNK_ 100
#define WARM_ 56                         // 0.95^56 * ~2.5 ≈ 0.14 abs err

typedef __bf16 bf16x8 __attribute__((ext_vector_type(8)));
typedef float f32x4 __attribute__((ext_vector_type(4)));

// ---------------- K1: fused GEMM + EMA scan + zero/out writer --------------
// Block: 256 thr (4 waves). Wave w owns b-range [w*16, w*16+16), all 4 t's
// of each 4-step group, and the block's 16-neuron slab.
__global__ __launch_bounds__(256) void k_fused(
    const float* __restrict__ x, const float* __restrict__ Win,
    const float* __restrict__ scale_p, const float* __restrict__ bout,
    float* __restrict__ out, float* __restrict__ spikes,
    float* __restrict__ volt, float* __restrict__ psc,
    float* __restrict__ filt, int* __restrict__ flagmax)
{
  const int tid = threadIdx.x;
  const int slab = blockIdx.x, chunk = blockIdx.y;
  const int nbase = slab * 16;
  const float sc = *scale_p;

  if (slab == 0 && chunk == 0) {       // output = b_out exactly
    for (int i = tid; i < B_ * O_; i += 256) out[i] = bout[i % O_];
  }

  const int wave = tid >> 6, lane = tid & 63;
  const int quad = lane >> 4, l16 = lane & 15;
  const int n = nbase + l16;           // this lane's MFMA column

  // hoist B fragments: Win[n][kb*32 + quad*8 .. +8] as bf16, 4 k-blocks
  bf16x8 bfrag[4];
#pragma unroll
  for (int kb = 0; kb < 4; ++kb) {
    const float4* src = (const float4*)(Win + (size_t)n * D_ + kb * 32 + quad * 8);
    float4 f0 = src[0], f1 = src[1];
    bf16x8 h;
    h[0] = (__bf16)f0.x; h[1] = (__bf16)f0.y; h[2] = (__bf16)f0.z; h[3] = (__bf16)f0.w;
    h[4] = (__bf16)f1.x; h[5] = (__bf16)f1.y; h[6] = (__bf16)f1.z; h[7] = (__bf16)f1.w;
    bfrag[kb] = h;
  }

  const int t0 = chunk * CHUNK_;
  const int tstart = (chunk == 0) ? 0 : t0 - WARM_;
  // EMA state: lane owns (b = wave*16 + quad*4 + r, n) for r in 0..3
  float v[4] = {-60.f, -60.f, -60.f, -60.f};
  float mx = -1e30f;

  for (int tg = tstart; tg < t0 + CHUNK_; tg += 4) {
    f32x4 acc[4];
#pragma unroll
    for (int ti = 0; ti < 4; ++ti) acc[ti] = (f32x4){0.f, 0.f, 0.f, 0.f};
#pragma unroll
    for (int ti = 0; ti < 4; ++ti) {
      const size_t mrow = (size_t)(tg + ti) * B_ + wave * 16 + l16;  // A row
#pragma unroll
      for (int kb = 0; kb < 4; ++kb) {
        const float4* ax = (const float4*)(x + mrow * D_ + kb * 32 + quad * 8);
        float4 a0 = ax[0], a1 = ax[1];
        bf16x8 af;
        af[0] = (__bf16)(a0.x * sc); af[1] = (__bf16)(a0.y * sc);
        af[2] = (__bf16)(a0.z * sc); af[3] = (__bf16)(a0.w * sc);
        af[4] = (__bf16)(a1.x * sc); af[5] = (__bf16)(a1.y * sc);
        af[6] = (__bf16)(a1.z * sc); af[7] = (__bf16)(a1.w * sc);
        acc[ti] = __builtin_amdgcn_mfma_f32_16x16x32_bf16(af, bfrag[kb], acc[ti], 0, 0, 0);
      }
    }
    const bool live = (tg >= t0);
    // EMA update; C/D layout: col = lane&15, row(b-offset) = quad*4 + r
#pragma unroll
    for (int ti = 0; ti < 4; ++ti) {
#pragma unroll
      for (int r = 0; r < 4; ++r) {
        float I = acc[ti][r];
        mx = fmaxf(mx, I);
        v[r] = v[r] + 0.05f * (-60.f - v[r]) + 0.05f * I;
        if (live) {
          const int b = wave * 16 + quad * 4 + r;
          volt[(size_t)(tg + ti) * BN_ + (size_t)b * N_ + n] = v[r];
        }
      }
    }
    if (live) {
      // zero spikes/psc/filt over this group's region: 4t x 64b x 16n
      const float4 z = make_float4(0.f, 0.f, 0.f, 0.f);
#pragma unroll
      for (int j = 0; j < 4; ++j) {
        const int i = tid + j * 256;          // f4 index in [0,1024)
        const int t_off = i >> 8, r2 = i & 255;
        const int b = r2 >> 2, nq = r2 & 3;
        const size_t off = (size_t)(tg + t_off) * BN_ + (size_t)b * N_ + nbase + nq * 4;
        *(float4*)(spikes + off) = z;
        *(float4*)(psc + off) = z;
        *(float4*)(filt + off) = z;
      }
    }
  }

  if (flagmax) {
    for (int off = 32; off; off >>= 1) mx = fmaxf(mx, __shfl_xor(mx, off));
    if (lane == 0 && mx > 14.0f) atomicMax(flagmax, __float_as_int(mx));
  }
}

// ---------------- K2: full-dynamics fallback (runs only if maxI > 14) -------
// I_ext recomputed inline (x row staged in LDS, 128-FMA dot per element).
__global__ __launch_bounds__(512) void k_fallback(
    const float* __restrict__ x, const float* __restrict__ Win,
    const float* __restrict__ iscale, const float* __restrict__ Wrec,
    const float* __restrict__ Wout, const float* __restrict__ bout,
    const float* __restrict__ osc_p,
    float* out, float* spikes, float* volt, float* psc_o, float* filt,
    const int* __restrict__ flagmax)
{
  if (!(__int_as_float(*flagmax) > 14.0f)) return;  // poison 0xAA.. < 0 => exit
  const int b = blockIdx.x, n = threadIdx.x;
  __shared__ float sx[D_];
  __shared__ float s_sp[N_];
  __shared__ float red[N_];
  const float sc = *iscale;
  const float e_syn = expf(-0.2f), e_asc = expf(-1.0f / 700.0f), alpha = expf(-0.05f);
  float v = -60.f, asc = 0.f, rr = 0.f, psc = 0.f, f = 0.f, favg = 0.f, sprev = 0.f;
  int refc = 0;
  for (int t = 0; t < T_; ++t) {
    if (n < D_) sx[n] = x[((size_t)t * B_ + b) * D_ + n] * sc;
    s_sp[n] = sprev;
    int cnt = __syncthreads_count(sprev > 0.f);
    float Iext = 0.f;
    for (int d = 0; d < D_; ++d) Iext += sx[d] * Win[(size_t)n * D_ + d];
    float rec = 0.f;
    if (cnt > 0)
      for (int m = 0; m < N_; ++m) rec += s_sp[m] * Wrec[(size_t)n * N_ + m];
    rr = rr * e_syn + rec;
    psc = psc * e_syn + 0.2f * rr;
    float I = Iext + psc + asc;
    v = (v + 0.05f * (-60.f - v)) + 0.05f * I;
    bool in_ref = refc > 0;
    if (in_ref) v = -60.f;
    float s = (!in_ref && (v - (-45.f) >= 0.f)) ? 1.f : 0.f;
    v = v * (1.f - s) + (-60.f) * s;
    refc = (s > 0.f) ? 5 : (refc > 0 ? refc - 1 : 0);
    asc = asc * e_asc + (-0.2f) * s;
    const size_t idx = (size_t)t * BN_ + (size_t)b * N_ + n;
    spikes[idx] = s; volt[idx] = v; psc_o[idx] = psc;
    f = (t == 0) ? s : (alpha * f + (1.f - alpha) * s);
    filt[idx] = f;
    if (t >= 200) favg += f;
    sprev = s;
    __syncthreads();
  }
  favg = favg / 800.f;
  float a_s = favg * (*osc_p);
  for (int o = 0; o < O_; ++o) {
    red[n] = a_s * Wout[o * N_ + n];
    __syncthreads();
    for (int st = 256; st; st >>= 1) {
      if (n < st) red[n] += red[n + st];
      __syncthreads();
    }
    if (n == 0) out[b * O_ + o] = red[0] + bout[o];
    __syncthreads();
  }
}

extern "C" void kernel_launch(void* const* d_in, const int* in_sizes, int n_in,
                              void* d_out, int out_size, void* d_ws, size_t ws_size,
                              hipStream_t stream) {
  const float* x      = (const float*)d_in[0];
  const float* Win    = (const float*)d_in[1];
  const float* iscale = (const float*)d_in[2];
  const float* Wrec   = (const float*)d_in[3];
  const float* Wout   = (const float*)d_in[4];
  const float* bout   = (const float*)d_in[5];
  const float* oscale = (const float*)d_in[6];

  float* out    = (float*)d_out;
  float* spikes = out + B_ * O_;
  float* volt   = spikes + S_;
  float* psc    = volt + S_;
  float* filt   = psc + S_;

  const bool has_flag = ws_size >= 4;
  int* flag = has_flag ? (int*)d_ws : nullptr;   // poison 0xAA.. reads as <0

  k_fused<<<dim3(NSLABS_, NCHUNK_), 256, 0, stream>>>(
      x, Win, iscale, bout, out, spikes, volt, psc, filt, flag);

  if (has_flag)
    k_fallback<<<B_, N_, 0, stream>>>(x, Win, iscale, Wrec, Wout, bout, oscale,
                                      out, spikes, volt, psc, filt, flag);
}

// Round 4
// 634.748 us; speedup vs baseline: 1.3698x; 1.3698x over previous
//
#include <hip/hip_runtime.h>
#include <hip/hip_bf16.h>

// ---------------------------------------------------------------------------
// GLIF3 RSNN. KEY INSIGHT: with these inputs the network is provably silent:
//   a spike needs EMA(I_ext) >= 15 (V_TH-V_RESET), but
//   |I_ext| <= sum_d max(W_in,0) ~ 6.3 absolute worst case.
// So spikes/psc/filtered are EXACTLY zero, output == b_out exactly, and
// voltage is an independent per-(b,n) linear EMA of I_ext (abs tol ~1.235).
//
// R4: latency-fix of the R3 fusion (R3: 5 waves/CU, serial load->cvt->MFMA
// chain -> 438 us at 1.7 TB/s). Changes: (1) prepass converts x*scale to
// bf16 once (16.4 MB, L2/L3-resident), (2) 2560 single-wave blocks
// (32n-slab x 16b-group x 25t-chunk) -> 10 waves/CU, (3) explicit t+1
// prefetch, (4) zeros via the 6.4 TB/s fill path; fused writes volt only.
// Safety: fused kernel atomicMaxes a ws flag if any I > 14; full-dynamics
// fallback runs only then (ws 0xAA poison decodes negative => silent path).
// Timed-window floor: harness poison ~450 us (2 GB ws + 524 MB out fills).
// ---------------------------------------------------------------------------

#define T_ 1000
#define B_ 64
#define D_ 128
#define N_ 512
#define O_ 10
#define BN_ (B_ * N_)                    // 32768
#define S_ ((size_t)T_ * BN_)            // 32,768,000 elems per big output
#define XE_ ((size_t)T_ * B_ * D_)       // 8,192,000 x elements

#define CHUNK_ 25
#define NCHUNK_ 40
#define WARM_ 56                         // 0.95^56*3.2 ~ 0.18 abs err

typedef __bf16 bf16x8 __attribute__((ext_vector_type(8)));
typedef float f32x4 __attribute__((ext_vector_type(4)));

// ---------------- K0: prepass — x*scale -> bf16, plus out = b_out ----------
__global__ __launch_bounds__(256) void k_prep(
    const float* __restrict__ x, const float* __restrict__ scale_p,
    __bf16* __restrict__ xb, const float* __restrict__ bout,
    float* __restrict__ out)
{
  if (blockIdx.x == 0) {
    for (int i = threadIdx.x; i < B_ * O_; i += 256) out[i] = bout[i % O_];
  }
  const float sc = *scale_p;
  const size_t i = ((size_t)blockIdx.x * 256 + threadIdx.x) * 8;
  const float4* s = (const float4*)(x + i);
  float4 a = s[0], b = s[1];
  bf16x8 h;
  h[0] = (__bf16)(a.x * sc); h[1] = (__bf16)(a.y * sc);
  h[2] = (__bf16)(a.z * sc); h[3] = (__bf16)(a.w * sc);
  h[4] = (__bf16)(b.x * sc); h[5] = (__bf16)(b.y * sc);
  h[6] = (__bf16)(b.z * sc); h[7] = (__bf16)(b.w * sc);
  *(bf16x8*)(xb + i) = h;
}

// ---------------- K1: fused MFMA-GEMM + voltage EMA ------------------------
// One wave per block. Block (x = slab*4+bgroup, y = chunk):
//   16 b x 32 n tile, t in [max(0,25c-56), 25c+25), live t >= 25c.
// A-frag: lane(l16,quad) holds xb[t, g*16+l16, quad*8+kb*32 ..+8] (bf16x8).
// B-frag (hoisted): Win[slab*32+h*16+l16][quad*8+kb*32 ..+8].
// C/D: row(b-offset) = quad*4+r, col(n-offset) = h*16+l16.  [layout verified
// end-to-end in R1/R3 passing runs]
__global__ __launch_bounds__(64) void k_fused_scan(
    const __bf16* __restrict__ xb, const float* __restrict__ Win,
    float* __restrict__ volt, int* __restrict__ flagmax)
{
  const int slab = blockIdx.x >> 2, g = blockIdx.x & 3;
  const int chunk = blockIdx.y;
  const int lane = threadIdx.x;
  const int quad = lane >> 4, l16 = lane & 15;

  // hoist B fragments (f32 -> bf16), 2 n-halves x 4 k-blocks
  bf16x8 bfrag[2][4];
#pragma unroll
  for (int h = 0; h < 2; ++h) {
    const float* wr = Win + (size_t)(slab * 32 + h * 16 + l16) * D_ + quad * 8;
#pragma unroll
    for (int kb = 0; kb < 4; ++kb) {
      const float4* src = (const float4*)(wr + kb * 32);
      float4 f0 = src[0], f1 = src[1];
      bf16x8 hh;
      hh[0] = (__bf16)f0.x; hh[1] = (__bf16)f0.y; hh[2] = (__bf16)f0.z; hh[3] = (__bf16)f0.w;
      hh[4] = (__bf16)f1.x; hh[5] = (__bf16)f1.y; hh[6] = (__bf16)f1.z; hh[7] = (__bf16)f1.w;
      bfrag[h][kb] = hh;
    }
  }

  const int t0 = chunk * CHUNK_;
  const int tstart = (t0 - WARM_ > 0) ? t0 - WARM_ : 0;
  const int tend = t0 + CHUNK_;

  float v[2][4];
#pragma unroll
  for (int h = 0; h < 2; ++h)
#pragma unroll
    for (int r = 0; r < 4; ++r) v[h][r] = -60.f;
  float mx = -1e30f;

  const __bf16* xp = xb + ((size_t)tstart * B_ + g * 16 + l16) * D_ + quad * 8;
  bf16x8 cur[4];
#pragma unroll
  for (int kb = 0; kb < 4; ++kb) cur[kb] = *(const bf16x8*)(xp + kb * 32);

  for (int t = tstart; t < tend; ++t) {
    const __bf16* xq = xp + B_ * D_;
    bf16x8 nxt[4];
    if (t + 1 < tend) {
#pragma unroll
      for (int kb = 0; kb < 4; ++kb) nxt[kb] = *(const bf16x8*)(xq + kb * 32);
    }
    f32x4 acc0 = (f32x4){0.f, 0.f, 0.f, 0.f};
    f32x4 acc1 = (f32x4){0.f, 0.f, 0.f, 0.f};
#pragma unroll
    for (int kb = 0; kb < 4; ++kb) {
      acc0 = __builtin_amdgcn_mfma_f32_16x16x32_bf16(cur[kb], bfrag[0][kb], acc0, 0, 0, 0);
      acc1 = __builtin_amdgcn_mfma_f32_16x16x32_bf16(cur[kb], bfrag[1][kb], acc1, 0, 0, 0);
    }
    const bool live = (t >= t0);
    float* vbase = volt + (size_t)t * BN_
                 + (size_t)(g * 16 + quad * 4) * N_ + slab * 32 + l16;
#pragma unroll
    for (int h = 0; h < 2; ++h) {
#pragma unroll
      for (int r = 0; r < 4; ++r) {
        const float I = h ? acc1[r] : acc0[r];
        const float nv = fmaf(0.95f, v[h][r], 0.05f * (I - 60.f));
        v[h][r] = nv;
        if (live) {
          mx = fmaxf(mx, I);
          vbase[(size_t)r * N_ + h * 16] = nv;
        }
      }
    }
#pragma unroll
    for (int kb = 0; kb < 4; ++kb) cur[kb] = nxt[kb];
    xp = xq;
  }

  if (flagmax) {
    for (int off = 32; off; off >>= 1) mx = fmaxf(mx, __shfl_xor(mx, off));
    if (lane == 0 && mx > 14.0f) atomicMax(flagmax, __float_as_int(mx));
  }
}

// ---------------- K2: full-dynamics fallback (runs only if maxI > 14) -------
// Exact dynamics from f32 x; overwrites every output. Never runs when silent.
__global__ __launch_bounds__(512) void k_fallback(
    const float* __restrict__ x, const float* __restrict__ Win,
    const float* __restrict__ iscale, const float* __restrict__ Wrec,
    const float* __restrict__ Wout, const float* __restrict__ bout,
    const float* __restrict__ osc_p,
    float* out, float* spikes, float* volt, float* psc_o, float* filt,
    const int* __restrict__ flagmax)
{
  if (!(__int_as_float(*flagmax) > 14.0f)) return;  // poison 0xAA.. < 0 => exit
  const int b = blockIdx.x, n = threadIdx.x;
  __shared__ float sx[D_];
  __shared__ float s_sp[N_];
  __shared__ float red[N_];
  const float sc = *iscale;
  const float e_syn = expf(-0.2f), e_asc = expf(-1.0f / 700.0f), alpha = expf(-0.05f);
  float v = -60.f, asc = 0.f, rr = 0.f, psc = 0.f, f = 0.f, favg = 0.f, sprev = 0.f;
  int refc = 0;
  for (int t = 0; t < T_; ++t) {
    if (n < D_) sx[n] = x[((size_t)t * B_ + b) * D_ + n] * sc;
    s_sp[n] = sprev;
    int cnt = __syncthreads_count(sprev > 0.f);
    float Iext = 0.f;
    for (int d = 0; d < D_; ++d) Iext += sx[d] * Win[(size_t)n * D_ + d];
    float rec = 0.f;
    if (cnt > 0)
      for (int m = 0; m < N_; ++m) rec += s_sp[m] * Wrec[(size_t)n * N_ + m];
    rr = rr * e_syn + rec;
    psc = psc * e_syn + 0.2f * rr;
    float I = Iext + psc + asc;
    v = (v + 0.05f * (-60.f - v)) + 0.05f * I;
    bool in_ref = refc > 0;
    if (in_ref) v = -60.f;
    float s = (!in_ref && (v - (-45.f) >= 0.f)) ? 1.f : 0.f;
    v = v * (1.f - s) + (-60.f) * s;
    refc = (s > 0.f) ? 5 : (refc > 0 ? refc - 1 : 0);
    asc = asc * e_asc + (-0.2f) * s;
    const size_t idx = (size_t)t * BN_ + (size_t)b * N_ + n;
    spikes[idx] = s; volt[idx] = v; psc_o[idx] = psc;
    f = (t == 0) ? s : (alpha * f + (1.f - alpha) * s);
    filt[idx] = f;
    if (t >= 200) favg += f;
    sprev = s;
    __syncthreads();
  }
  favg = favg / 800.f;
  float a_s = favg * (*osc_p);
  for (int o = 0; o < O_; ++o) {
    red[n] = a_s * Wout[o * N_ + n];
    __syncthreads();
    for (int st = 256; st; st >>= 1) {
      if (n < st) red[n] += red[n + st];
      __syncthreads();
    }
    if (n == 0) out[b * O_ + o] = red[0] + bout[o];
    __syncthreads();
  }
}

extern "C" void kernel_launch(void* const* d_in, const int* in_sizes, int n_in,
                              void* d_out, int out_size, void* d_ws, size_t ws_size,
                              hipStream_t stream) {
  const float* x      = (const float*)d_in[0];
  const float* Win    = (const float*)d_in[1];
  const float* iscale = (const float*)d_in[2];
  const float* Wrec   = (const float*)d_in[3];
  const float* Wout   = (const float*)d_in[4];
  const float* bout   = (const float*)d_in[5];
  const float* oscale = (const float*)d_in[6];

  float* out    = (float*)d_out;
  float* spikes = out + B_ * O_;
  float* volt   = spikes + S_;
  float* psc    = volt + S_;
  float* filt   = psc + S_;

  const bool has_flag = ws_size >= 4;
  int* flag = has_flag ? (int*)d_ws : nullptr;   // poison 0xAA.. reads as <0
  const bool ws_xb = ws_size >= (size_t)256 + XE_ * sizeof(__bf16);
  __bf16* xb = ws_xb ? (__bf16*)((char*)d_ws + 256) : (__bf16*)filt;

  // prepass: x*scale -> bf16 (+ out writer)
  k_prep<<<(int)(XE_ / 8 / 256), 256, 0, stream>>>(x, iscale, xb, bout, out);

  // zero outputs via the fast fill path (spikes, psc now; filt after fused)
  hipMemsetAsync(spikes, 0, S_ * 4, stream);
  hipMemsetAsync(psc, 0, S_ * 4, stream);

  k_fused_scan<<<dim3(64, NCHUNK_), 64, 0, stream>>>(xb, Win, volt, flag);

  hipMemsetAsync(filt, 0, S_ * 4, stream);   // after fused: xb may alias filt

  if (has_flag)
    k_fallback<<<B_, N_, 0, stream>>>(x, Win, iscale, Wrec, Wout, bout, oscale,
                                      out, spikes, volt, psc, filt, flag);
}